// Round 5
// baseline (348.957 us; speedup 1.0000x reference)
//
#include <hip/hip_runtime.h>

#define NN 100000
#define NE 3200000
#define DF 128
#define HID 32
#define NC 2
#define NB 391   // ceil(NN/256)
#define RB 8     // edges per thread in k_rank
#define FB 4     // edges per thread in k_fill

// ws layout (4-byte words):
// [0, NN)               dis (float): rsqrt(deg+1)
// [NN, 2NN)             rofs (int): counts -> exclusive scan = row STARTS (never mutated after)
// [2NN, 2NN+1024)       bsum (int): per-block scan sums
// [2NN+1024, 4NN+1024)  h2 (float [NN,2])
// [4NN+1024, +NE)       csr (int): src indices grouped by dst
// [4NN+1024+NE, +32NN)  h1 (float [NN,32]); first NE words double as rank[] until k_gemm1
// total 36NN + NE + 1024 = 27.2 MB

__global__ void k_zero(int4* __restrict__ p, int n4) {
    int i = blockIdx.x * blockDim.x + threadIdx.x;
    if (i < n4) p[i] = make_int4(0, 0, 0, 0);
}

// count degree AND record each edge's rank within its dst.
// 8 edges/thread, grid-strided: 8 independent atomics in flight per lane (MLP).
__global__ void k_rank(const int* __restrict__ dst, unsigned* __restrict__ cnt,
                       int* __restrict__ rank) {
    const int T = NE / RB;  // 400000
    int t = blockIdx.x * blockDim.x + threadIdx.x;
    if (t >= T) return;
    int d[RB];
    unsigned r[RB];
#pragma unroll
    for (int i = 0; i < RB; ++i) d[i] = dst[t + i * T];
#pragma unroll
    for (int i = 0; i < RB; ++i) r[i] = atomicAdd(&cnt[d[i]], 1u);
#pragma unroll
    for (int i = 0; i < RB; ++i) rank[t + i * T] = (int)r[i];
}

// per-block exclusive scan of counts; block totals -> bsum; dis fused (deg = pre-scan value)
__global__ void k_scan1(int* __restrict__ rofs, int* __restrict__ bsum,
                        float* __restrict__ dis) {
    __shared__ int sm[256];
    int i = blockIdx.x * 256 + threadIdx.x;
    int v = (i < NN) ? rofs[i] : 0;
    if (i < NN) dis[i] = rsqrtf((float)(v + 1));  // +1 = self-loop
    sm[threadIdx.x] = v;
    __syncthreads();
    for (int off = 1; off < 256; off <<= 1) {
        int t = (threadIdx.x >= off) ? sm[threadIdx.x - off] : 0;
        __syncthreads();
        sm[threadIdx.x] += t;
        __syncthreads();
    }
    if (i < NN) rofs[i] = sm[threadIdx.x] - v;  // exclusive
    if (threadIdx.x == 255) bsum[blockIdx.x] = sm[255];
}

__global__ void k_scan2(int* __restrict__ bsum) {
    __shared__ int sm[512];
    int v = (threadIdx.x < NB) ? bsum[threadIdx.x] : 0;
    sm[threadIdx.x] = v;
    __syncthreads();
    for (int off = 1; off < 512; off <<= 1) {
        int t = (threadIdx.x >= off) ? sm[threadIdx.x - off] : 0;
        __syncthreads();
        sm[threadIdx.x] += t;
        __syncthreads();
    }
    if (threadIdx.x < NB) bsum[threadIdx.x] = sm[threadIdx.x] - v;
}

__global__ void k_scan3(int* __restrict__ rofs, const int* __restrict__ bsum) {
    int i = blockIdx.x * 256 + threadIdx.x;
    if (i < NN) rofs[i] += bsum[blockIdx.x];
}

// atomic-free CSR fill, 4 edges/thread for load MLP
__global__ void k_fill(const int* __restrict__ eidx, const int* __restrict__ rofs,
                       const int* __restrict__ rank, int* __restrict__ csr) {
    const int T = NE / FB;  // 800000
    int t = blockIdx.x * blockDim.x + threadIdx.x;
    if (t >= T) return;
    int s[FB], d[FB], rk[FB], ro[FB];
#pragma unroll
    for (int i = 0; i < FB; ++i) s[i] = eidx[t + i * T];
#pragma unroll
    for (int i = 0; i < FB; ++i) d[i] = eidx[NE + t + i * T];
#pragma unroll
    for (int i = 0; i < FB; ++i) rk[i] = rank[t + i * T];
#pragma unroll
    for (int i = 0; i < FB; ++i) ro[i] = rofs[d[i]];
#pragma unroll
    for (int i = 0; i < FB; ++i) csr[ro[i] + rk[i]] = s[i];
}

// h1 = x @ W1 (W1 wave-uniform -> scalar loads; HBM-bound on x)
__global__ __launch_bounds__(256) void k_gemm1(const float* __restrict__ x,
                                               const float* __restrict__ W1,
                                               float* __restrict__ h1) {
    int r = blockIdx.x * blockDim.x + threadIdx.x;
    if (r >= NN) return;
    const float* xr = x + (size_t)r * DF;
    float acc[HID];
#pragma unroll
    for (int c = 0; c < HID; ++c) acc[c] = 0.f;
#pragma unroll
    for (int k = 0; k < DF; k += 4) {
        float4 xv = *reinterpret_cast<const float4*>(xr + k);
#pragma unroll
        for (int c = 0; c < HID; ++c) {
            acc[c] += xv.x * W1[(k + 0) * HID + c];
            acc[c] += xv.y * W1[(k + 1) * HID + c];
            acc[c] += xv.z * W1[(k + 2) * HID + c];
            acc[c] += xv.w * W1[(k + 3) * HID + c];
        }
    }
    float* hr = h1 + (size_t)r * HID;
#pragma unroll
    for (int c = 0; c < HID; c += 4)
        *reinterpret_cast<float4*>(hr + c) = make_float4(acc[c], acc[c + 1], acc[c + 2], acc[c + 3]);
}

// gather-aggregate layer 1, fused with +b1, relu, @W2, 8-lane reduce -> h2
__global__ void k_gather1(const int* __restrict__ rofs, const int* __restrict__ csr,
                          const float* __restrict__ dis, const float* __restrict__ h1,
                          const float* __restrict__ b1, const float* __restrict__ W2,
                          float* __restrict__ h2) {
    int t = blockIdx.x * blockDim.x + threadIdx.x;
    int r = t >> 3;
    if (r >= NN) return;
    int p = t & 7;
    int start = rofs[r];
    int end = (r == NN - 1) ? NE : rofs[r + 1];
    float dr = dis[r];
    float a0 = 0.f, a1 = 0.f, a2 = 0.f, a3 = 0.f;
    int j = start;
    for (; j + 1 < end; j += 2) {
        int s0 = csr[j], s1 = csr[j + 1];
        float n0 = dr * dis[s0], n1 = dr * dis[s1];
        float4 v0 = *reinterpret_cast<const float4*>(h1 + (size_t)s0 * HID + p * 4);
        float4 v1 = *reinterpret_cast<const float4*>(h1 + (size_t)s1 * HID + p * 4);
        a0 += v0.x * n0 + v1.x * n1;
        a1 += v0.y * n0 + v1.y * n1;
        a2 += v0.z * n0 + v1.z * n1;
        a3 += v0.w * n0 + v1.w * n1;
    }
    if (j < end) {
        int s0 = csr[j];
        float n0 = dr * dis[s0];
        float4 v0 = *reinterpret_cast<const float4*>(h1 + (size_t)s0 * HID + p * 4);
        a0 += v0.x * n0; a1 += v0.y * n0; a2 += v0.z * n0; a3 += v0.w * n0;
    }
    float self = dr * dr;
    float4 hv = *reinterpret_cast<const float4*>(h1 + (size_t)r * HID + p * 4);
    a0 += hv.x * self; a1 += hv.y * self; a2 += hv.z * self; a3 += hv.w * self;
    float4 bv = *reinterpret_cast<const float4*>(b1 + p * 4);
    float v0 = fmaxf(a0 + bv.x, 0.f);
    float v1 = fmaxf(a1 + bv.y, 0.f);
    float v2 = fmaxf(a2 + bv.z, 0.f);
    float v3 = fmaxf(a3 + bv.w, 0.f);
    int c = p * 4;
    float o0 = v0 * W2[(c + 0) * NC + 0] + v1 * W2[(c + 1) * NC + 0] +
               v2 * W2[(c + 2) * NC + 0] + v3 * W2[(c + 3) * NC + 0];
    float o1 = v0 * W2[(c + 0) * NC + 1] + v1 * W2[(c + 1) * NC + 1] +
               v2 * W2[(c + 2) * NC + 1] + v3 * W2[(c + 3) * NC + 1];
    o0 += __shfl_xor(o0, 1); o1 += __shfl_xor(o1, 1);
    o0 += __shfl_xor(o0, 2); o1 += __shfl_xor(o1, 2);
    o0 += __shfl_xor(o0, 4); o1 += __shfl_xor(o1, 4);
    if (p == 0) {
        h2[2 * (size_t)r + 0] = o0;
        h2[2 * (size_t)r + 1] = o1;
    }
}

// gather-aggregate layer 2 (+b2) fused with log_softmax -> out
__global__ void k_gather2(const int* __restrict__ rofs, const int* __restrict__ csr,
                          const float* __restrict__ dis, const float* __restrict__ h2,
                          const float* __restrict__ b2, float* __restrict__ out) {
    int r = blockIdx.x * blockDim.x + threadIdx.x;
    if (r >= NN) return;
    int start = rofs[r];
    int end = (r == NN - 1) ? NE : rofs[r + 1];
    float dr = dis[r];
    float a0 = 0.f, a1 = 0.f;
    for (int j = start; j < end; ++j) {
        int s = csr[j];
        float nrm = dr * dis[s];
        float2 v = *reinterpret_cast<const float2*>(h2 + 2 * (size_t)s);
        a0 += v.x * nrm;
        a1 += v.y * nrm;
    }
    float self = dr * dr;
    float2 hv = *reinterpret_cast<const float2*>(h2 + 2 * (size_t)r);
    float l0 = a0 + hv.x * self + b2[0];
    float l1 = a1 + hv.y * self + b2[1];
    float m = fmaxf(l0, l1);
    float lse = m + logf(expf(l0 - m) + expf(l1 - m));
    out[2 * (size_t)r + 0] = l0 - lse;
    out[2 * (size_t)r + 1] = l1 - lse;
}

extern "C" void kernel_launch(void* const* d_in, const int* in_sizes, int n_in,
                              void* d_out, int out_size, void* d_ws, size_t ws_size,
                              hipStream_t stream) {
    const float* x  = (const float*)d_in[0];
    const int* ei   = (const int*)d_in[1];   // [2, NE] int32
    const float* W1 = (const float*)d_in[2];
    const float* b1 = (const float*)d_in[3];
    const float* W2 = (const float*)d_in[4];
    const float* b2 = (const float*)d_in[5];
    float* out      = (float*)d_out;

    float* ws  = (float*)d_ws;
    float* dis = ws;
    int* rofs  = (int*)(ws + (size_t)NN);
    int* bsum  = (int*)(ws + (size_t)2 * NN);
    float* h2  = ws + (size_t)2 * NN + 1024;
    int* csr   = (int*)(ws + (size_t)4 * NN + 1024);
    float* h1  = ws + (size_t)4 * NN + 1024 + NE;
    int* rank  = (int*)h1;   // NE words; dead before k_gemm1 writes h1

    k_zero<<<(NN / 4 + 255) / 256, 256, 0, stream>>>((int4*)rofs, NN / 4);
    k_rank<<<(NE / RB + 255) / 256, 256, 0, stream>>>(ei + NE, (unsigned*)rofs, rank);
    k_scan1<<<NB, 256, 0, stream>>>(rofs, bsum, dis);
    k_scan2<<<1, 512, 0, stream>>>(bsum);
    k_scan3<<<NB, 256, 0, stream>>>(rofs, bsum);
    k_fill<<<(NE / FB + 255) / 256, 256, 0, stream>>>(ei, rofs, rank, csr);
    k_gemm1<<<NB, 256, 0, stream>>>(x, W1, h1);
    k_gather1<<<(NN * 8 + 255) / 256, 256, 0, stream>>>(rofs, csr, dis, h1, b1, W2, h2);
    k_gather2<<<NB, 256, 0, stream>>>(rofs, csr, dis, h2, b2, out);
}

// Round 6
// 289.449 us; speedup vs baseline: 1.2056x; 1.2056x over previous
//
#include <hip/hip_runtime.h>

#define NN 100000
#define NE 3200000
#define DF 128
#define HID 32
#define NC 2
#define NB 391     // ceil(NN/256): blocks for node-parallel kernels
#define NBUK 391   // buckets of 256 nodes: bucket = dst >> 8
#define EB 8192    // edges per block in k_hist/k_part (391 blocks cover NE)

// ws layout (4-byte words):
// [0, NN)                 dis (float): rsqrt(deg+1)
// [NN, 2NN)               rofs (int): global row starts (CSR)
// [2NN, 2NN+400)          btot (uint): bucket totals
// [2NN+400, 2NN+800)      bstart (int): bucket starts (392 used)
// [2NN+800, 2NN+1200)     cursor (int): bucket cursors (mutated by k_part)
// [2NN+1200, 4NN+1200)    h2 (float [NN,2])
// [4NN+1200, +NE)         csr (int): src indices grouped by dst
// [4NN+1200+NE, +32NN)    h1 (float [NN,32]); doubles as scr (packed edges) until k_gemm1
// total 36NN + NE + 1200 = 6,801,200 words = 27.2 MB

__global__ void k_z(unsigned* __restrict__ p, int n) {
    int i = blockIdx.x * blockDim.x + threadIdx.x;
    if (i < n) p[i] = 0u;
}

// per-block LDS histogram over buckets -> global bucket totals (non-returning adds)
__global__ __launch_bounds__(256) void k_hist(const int* __restrict__ dst,
                                              unsigned* __restrict__ btot) {
    __shared__ unsigned h[NBUK];
    for (int i = threadIdx.x; i < NBUK; i += 256) h[i] = 0u;
    __syncthreads();
    int base = blockIdx.x * EB;
#pragma unroll
    for (int i = 0; i < EB / 256; ++i) {
        int e = base + i * 256 + threadIdx.x;
        if (e < NE) atomicAdd(&h[dst[e] >> 8], 1u);
    }
    __syncthreads();
    for (int i = threadIdx.x; i < NBUK; i += 256)
        if (h[i]) atomicAdd(&btot[i], h[i]);
}

// single-block exclusive scan of bucket totals -> bstart, cursor
__global__ void k_bscan(const unsigned* __restrict__ btot, int* __restrict__ bstart,
                        int* __restrict__ cursor) {
    __shared__ int sm[512];
    int v = (threadIdx.x < NBUK) ? (int)btot[threadIdx.x] : 0;
    sm[threadIdx.x] = v;
    __syncthreads();
    for (int off = 1; off < 512; off <<= 1) {
        int t = (threadIdx.x >= off) ? sm[threadIdx.x - off] : 0;
        __syncthreads();
        sm[threadIdx.x] += t;
        __syncthreads();
    }
    if (threadIdx.x < NBUK) {
        int excl = sm[threadIdx.x] - v;
        bstart[threadIdx.x] = excl;
        cursor[threadIdx.x] = excl;
    }
    if (threadIdx.x == 0) bstart[NBUK] = NE;
}

// partition edges into bucket regions of scr; packed word = src | (dst&255)<<17
__global__ __launch_bounds__(256) void k_part(const int* __restrict__ eidx,
                                              int* __restrict__ cursor,
                                              unsigned* __restrict__ scr) {
    __shared__ unsigned h[NBUK];
    for (int i = threadIdx.x; i < NBUK; i += 256) h[i] = 0u;
    __syncthreads();
    int base = blockIdx.x * EB;
    int d[EB / 256];
#pragma unroll
    for (int i = 0; i < EB / 256; ++i) {
        int e = base + i * 256 + threadIdx.x;
        d[i] = (e < NE) ? eidx[NE + e] : -1;
        if (d[i] >= 0) atomicAdd(&h[d[i] >> 8], 1u);
    }
    __syncthreads();
    // reserve global space per (block,bucket): one returning atomic per nonzero bin
    for (int i = threadIdx.x; i < NBUK; i += 256) {
        unsigned c = h[i];
        h[i] = c ? atomicAdd((unsigned*)&cursor[i], c) : 0u;
    }
    __syncthreads();
#pragma unroll
    for (int i = 0; i < EB / 256; ++i) {
        int e = base + i * 256 + threadIdx.x;
        if (e < NE) {
            unsigned s = (unsigned)eidx[e];
            unsigned pos = atomicAdd(&h[d[i] >> 8], 1u);   // LDS returning atomic
            scr[pos] = s | ((unsigned)(d[i] & 255) << 17);
        }
    }
}

// one block per bucket: 256-bin LDS histogram -> rofs/dis + ranked scatter into csr
__global__ __launch_bounds__(256) void k_build(const unsigned* __restrict__ scr,
                                               const int* __restrict__ bstart,
                                               int* __restrict__ rofs, float* __restrict__ dis,
                                               int* __restrict__ csr) {
    int b = blockIdx.x;
    int cs = bstart[b], ce = bstart[b + 1];
    __shared__ unsigned h[256];
    __shared__ int sm[256];
    h[threadIdx.x] = 0u;
    __syncthreads();
    for (int j = cs + threadIdx.x; j < ce; j += 256)
        atomicAdd(&h[(scr[j] >> 17) & 255], 1u);
    __syncthreads();
    int v = (int)h[threadIdx.x];
    sm[threadIdx.x] = v;
    __syncthreads();
    for (int off = 1; off < 256; off <<= 1) {
        int t = (threadIdx.x >= off) ? sm[threadIdx.x - off] : 0;
        __syncthreads();
        sm[threadIdx.x] += t;
        __syncthreads();
    }
    int excl = sm[threadIdx.x] - v;
    int node = b * 256 + threadIdx.x;
    if (node < NN) {
        rofs[node] = cs + excl;
        dis[node] = rsqrtf((float)(v + 1));   // +1 = self-loop
    }
    __syncthreads();
    h[threadIdx.x] = (unsigned)(cs + excl);   // reuse as per-node cursor
    __syncthreads();
    for (int j = cs + threadIdx.x; j < ce; j += 256) {
        unsigned w = scr[j];
        unsigned pos = atomicAdd(&h[(w >> 17) & 255], 1u);
        csr[pos] = (int)(w & 0x1FFFFu);
    }
}

// h1 = x @ W1 (W1 wave-uniform -> scalar loads; HBM-bound on x)
__global__ __launch_bounds__(256) void k_gemm1(const float* __restrict__ x,
                                               const float* __restrict__ W1,
                                               float* __restrict__ h1) {
    int r = blockIdx.x * blockDim.x + threadIdx.x;
    if (r >= NN) return;
    const float* xr = x + (size_t)r * DF;
    float acc[HID];
#pragma unroll
    for (int c = 0; c < HID; ++c) acc[c] = 0.f;
#pragma unroll
    for (int k = 0; k < DF; k += 4) {
        float4 xv = *reinterpret_cast<const float4*>(xr + k);
#pragma unroll
        for (int c = 0; c < HID; ++c) {
            acc[c] += xv.x * W1[(k + 0) * HID + c];
            acc[c] += xv.y * W1[(k + 1) * HID + c];
            acc[c] += xv.z * W1[(k + 2) * HID + c];
            acc[c] += xv.w * W1[(k + 3) * HID + c];
        }
    }
    float* hr = h1 + (size_t)r * HID;
#pragma unroll
    for (int c = 0; c < HID; c += 4)
        *reinterpret_cast<float4*>(hr + c) = make_float4(acc[c], acc[c + 1], acc[c + 2], acc[c + 3]);
}

// gather-aggregate layer 1, fused with +b1, relu, @W2, 8-lane reduce -> h2
__global__ void k_gather1(const int* __restrict__ rofs, const int* __restrict__ csr,
                          const float* __restrict__ dis, const float* __restrict__ h1,
                          const float* __restrict__ b1, const float* __restrict__ W2,
                          float* __restrict__ h2) {
    int t = blockIdx.x * blockDim.x + threadIdx.x;
    int r = t >> 3;
    if (r >= NN) return;
    int p = t & 7;
    int start = rofs[r];
    int end = (r == NN - 1) ? NE : rofs[r + 1];
    float dr = dis[r];
    float a0 = 0.f, a1 = 0.f, a2 = 0.f, a3 = 0.f;
    int j = start;
    for (; j + 1 < end; j += 2) {
        int s0 = csr[j], s1 = csr[j + 1];
        float n0 = dr * dis[s0], n1 = dr * dis[s1];
        float4 v0 = *reinterpret_cast<const float4*>(h1 + (size_t)s0 * HID + p * 4);
        float4 v1 = *reinterpret_cast<const float4*>(h1 + (size_t)s1 * HID + p * 4);
        a0 += v0.x * n0 + v1.x * n1;
        a1 += v0.y * n0 + v1.y * n1;
        a2 += v0.z * n0 + v1.z * n1;
        a3 += v0.w * n0 + v1.w * n1;
    }
    if (j < end) {
        int s0 = csr[j];
        float n0 = dr * dis[s0];
        float4 v0 = *reinterpret_cast<const float4*>(h1 + (size_t)s0 * HID + p * 4);
        a0 += v0.x * n0; a1 += v0.y * n0; a2 += v0.z * n0; a3 += v0.w * n0;
    }
    float self = dr * dr;
    float4 hv = *reinterpret_cast<const float4*>(h1 + (size_t)r * HID + p * 4);
    a0 += hv.x * self; a1 += hv.y * self; a2 += hv.z * self; a3 += hv.w * self;
    float4 bv = *reinterpret_cast<const float4*>(b1 + p * 4);
    float v0 = fmaxf(a0 + bv.x, 0.f);
    float v1 = fmaxf(a1 + bv.y, 0.f);
    float v2 = fmaxf(a2 + bv.z, 0.f);
    float v3 = fmaxf(a3 + bv.w, 0.f);
    int c = p * 4;
    float o0 = v0 * W2[(c + 0) * NC + 0] + v1 * W2[(c + 1) * NC + 0] +
               v2 * W2[(c + 2) * NC + 0] + v3 * W2[(c + 3) * NC + 0];
    float o1 = v0 * W2[(c + 0) * NC + 1] + v1 * W2[(c + 1) * NC + 1] +
               v2 * W2[(c + 2) * NC + 1] + v3 * W2[(c + 3) * NC + 1];
    o0 += __shfl_xor(o0, 1); o1 += __shfl_xor(o1, 1);
    o0 += __shfl_xor(o0, 2); o1 += __shfl_xor(o1, 2);
    o0 += __shfl_xor(o0, 4); o1 += __shfl_xor(o1, 4);
    if (p == 0) {
        h2[2 * (size_t)r + 0] = o0;
        h2[2 * (size_t)r + 1] = o1;
    }
}

// gather-aggregate layer 2 (+b2) fused with log_softmax -> out
__global__ void k_gather2(const int* __restrict__ rofs, const int* __restrict__ csr,
                          const float* __restrict__ dis, const float* __restrict__ h2,
                          const float* __restrict__ b2, float* __restrict__ out) {
    int r = blockIdx.x * blockDim.x + threadIdx.x;
    if (r >= NN) return;
    int start = rofs[r];
    int end = (r == NN - 1) ? NE : rofs[r + 1];
    float dr = dis[r];
    float a0 = 0.f, a1 = 0.f;
    for (int j = start; j < end; ++j) {
        int s = csr[j];
        float nrm = dr * dis[s];
        float2 v = *reinterpret_cast<const float2*>(h2 + 2 * (size_t)s);
        a0 += v.x * nrm;
        a1 += v.y * nrm;
    }
    float self = dr * dr;
    float2 hv = *reinterpret_cast<const float2*>(h2 + 2 * (size_t)r);
    float l0 = a0 + hv.x * self + b2[0];
    float l1 = a1 + hv.y * self + b2[1];
    float m = fmaxf(l0, l1);
    float lse = m + logf(expf(l0 - m) + expf(l1 - m));
    out[2 * (size_t)r + 0] = l0 - lse;
    out[2 * (size_t)r + 1] = l1 - lse;
}

extern "C" void kernel_launch(void* const* d_in, const int* in_sizes, int n_in,
                              void* d_out, int out_size, void* d_ws, size_t ws_size,
                              hipStream_t stream) {
    const float* x  = (const float*)d_in[0];
    const int* ei   = (const int*)d_in[1];   // [2, NE] int32
    const float* W1 = (const float*)d_in[2];
    const float* b1 = (const float*)d_in[3];
    const float* W2 = (const float*)d_in[4];
    const float* b2 = (const float*)d_in[5];
    float* out      = (float*)d_out;

    float* ws       = (float*)d_ws;
    float* dis      = ws;
    int* rofs       = (int*)(ws + (size_t)NN);
    unsigned* btot  = (unsigned*)(ws + (size_t)2 * NN);
    int* bstart     = (int*)(ws + (size_t)2 * NN + 400);
    int* cursor     = (int*)(ws + (size_t)2 * NN + 800);
    float* h2       = ws + (size_t)2 * NN + 1200;
    int* csr        = (int*)(ws + (size_t)4 * NN + 1200);
    float* h1       = ws + (size_t)4 * NN + 1200 + NE;
    unsigned* scr   = (unsigned*)h1;   // NE words; consumed by k_build before k_gemm1 writes h1

    k_z<<<2, 256, 0, stream>>>(btot, NBUK);
    k_hist<<<391, 256, 0, stream>>>(ei + NE, btot);
    k_bscan<<<1, 512, 0, stream>>>(btot, bstart, cursor);
    k_part<<<391, 256, 0, stream>>>(ei, cursor, scr);
    k_build<<<NBUK, 256, 0, stream>>>(scr, bstart, rofs, dis, csr);
    k_gemm1<<<NB, 256, 0, stream>>>(x, W1, h1);
    k_gather1<<<(NN * 8 + 255) / 256, 256, 0, stream>>>(rofs, csr, dis, h1, b1, W2, h2);
    k_gather2<<<NB, 256, 0, stream>>>(rofs, csr, dis, h2, b2, out);
}

// Round 7
// 217.580 us; speedup vs baseline: 1.6038x; 1.3303x over previous
//
#include <hip/hip_runtime.h>
#include <hip/hip_fp16.h>

#define NN 100000
#define NE 3200000
#define DF 128
#define HID 32
#define NC 2
#define NB 391     // ceil(NN/256): blocks for node-parallel kernels
#define NBUK 391   // buckets of 256 nodes: bucket = dst >> 8
#define EB 8192    // edges per block in k_hist/k_part (391 blocks cover NE)

// ws layout (4-byte words):
// [0, NN)                 dis (float): rsqrt(deg+1)
// [NN, 2NN)               rofs (int): global row starts (CSR)
// [2NN, 2NN+400)          btot (uint): bucket totals
// [2NN+400, 2NN+800)      bstart (int): bucket starts (392 used)
// [2NN+800, 2NN+1200)     cursor (int): bucket cursors (mutated by k_part)
// [2NN+1200, 4NN+1200)    h2 (float [NN,2])
// [4NN+1200, +NE)         csr (int): src indices grouped by dst
// [4NN+1200+NE, +NE)      scr (packed edges, NE words); after k_build consumed,
//                         h1 (HALF [NN,32] = 16NN words) overwrites its head
// total 4NN + 2NE + 1200 = 6,801,200 words = 27.2 MB (unchanged)

__global__ void k_z(unsigned* __restrict__ p, int n) {
    int i = blockIdx.x * blockDim.x + threadIdx.x;
    if (i < n) p[i] = 0u;
}

// per-block LDS histogram over buckets -> global bucket totals (non-returning adds)
__global__ __launch_bounds__(256) void k_hist(const int* __restrict__ dst,
                                              unsigned* __restrict__ btot) {
    __shared__ unsigned h[NBUK];
    for (int i = threadIdx.x; i < NBUK; i += 256) h[i] = 0u;
    __syncthreads();
    int base = blockIdx.x * EB;
#pragma unroll
    for (int i = 0; i < EB / 256; ++i) {
        int e = base + i * 256 + threadIdx.x;
        if (e < NE) atomicAdd(&h[dst[e] >> 8], 1u);
    }
    __syncthreads();
    for (int i = threadIdx.x; i < NBUK; i += 256)
        if (h[i]) atomicAdd(&btot[i], h[i]);
}

// single-block exclusive scan of bucket totals -> bstart, cursor
__global__ void k_bscan(const unsigned* __restrict__ btot, int* __restrict__ bstart,
                        int* __restrict__ cursor) {
    __shared__ int sm[512];
    int v = (threadIdx.x < NBUK) ? (int)btot[threadIdx.x] : 0;
    sm[threadIdx.x] = v;
    __syncthreads();
    for (int off = 1; off < 512; off <<= 1) {
        int t = (threadIdx.x >= off) ? sm[threadIdx.x - off] : 0;
        __syncthreads();
        sm[threadIdx.x] += t;
        __syncthreads();
    }
    if (threadIdx.x < NBUK) {
        int excl = sm[threadIdx.x] - v;
        bstart[threadIdx.x] = excl;
        cursor[threadIdx.x] = excl;
    }
    if (threadIdx.x == 0) bstart[NBUK] = NE;
}

// partition edges into bucket regions of scr; packed word = src | (dst&255)<<17
__global__ __launch_bounds__(256) void k_part(const int* __restrict__ eidx,
                                              int* __restrict__ cursor,
                                              unsigned* __restrict__ scr) {
    __shared__ unsigned h[NBUK];
    for (int i = threadIdx.x; i < NBUK; i += 256) h[i] = 0u;
    __syncthreads();
    int base = blockIdx.x * EB;
    int d[EB / 256];
#pragma unroll
    for (int i = 0; i < EB / 256; ++i) {
        int e = base + i * 256 + threadIdx.x;
        d[i] = (e < NE) ? eidx[NE + e] : -1;
        if (d[i] >= 0) atomicAdd(&h[d[i] >> 8], 1u);
    }
    __syncthreads();
    // reserve global space per (block,bucket): one returning atomic per nonzero bin
    for (int i = threadIdx.x; i < NBUK; i += 256) {
        unsigned c = h[i];
        h[i] = c ? atomicAdd((unsigned*)&cursor[i], c) : 0u;
    }
    __syncthreads();
#pragma unroll
    for (int i = 0; i < EB / 256; ++i) {
        int e = base + i * 256 + threadIdx.x;
        if (e < NE) {
            unsigned s = (unsigned)eidx[e];
            unsigned pos = atomicAdd(&h[d[i] >> 8], 1u);   // LDS returning atomic
            scr[pos] = s | ((unsigned)(d[i] & 255) << 17);
        }
    }
}

// one block per bucket: 256-bin LDS histogram -> rofs/dis + ranked scatter into csr
__global__ __launch_bounds__(256) void k_build(const unsigned* __restrict__ scr,
                                               const int* __restrict__ bstart,
                                               int* __restrict__ rofs, float* __restrict__ dis,
                                               int* __restrict__ csr) {
    int b = blockIdx.x;
    int cs = bstart[b], ce = bstart[b + 1];
    __shared__ unsigned h[256];
    __shared__ int sm[256];
    h[threadIdx.x] = 0u;
    __syncthreads();
    for (int j = cs + threadIdx.x; j < ce; j += 256)
        atomicAdd(&h[(scr[j] >> 17) & 255], 1u);
    __syncthreads();
    int v = (int)h[threadIdx.x];
    sm[threadIdx.x] = v;
    __syncthreads();
    for (int off = 1; off < 256; off <<= 1) {
        int t = (threadIdx.x >= off) ? sm[threadIdx.x - off] : 0;
        __syncthreads();
        sm[threadIdx.x] += t;
        __syncthreads();
    }
    int excl = sm[threadIdx.x] - v;
    int node = b * 256 + threadIdx.x;
    if (node < NN) {
        rofs[node] = cs + excl;
        dis[node] = rsqrtf((float)(v + 1));   // +1 = self-loop
    }
    __syncthreads();
    h[threadIdx.x] = (unsigned)(cs + excl);   // reuse as per-node cursor
    __syncthreads();
    for (int j = cs + threadIdx.x; j < ce; j += 256) {
        unsigned w = scr[j];
        unsigned pos = atomicAdd(&h[(w >> 17) & 255], 1u);
        csr[pos] = (int)(w & 0x1FFFFu);
    }
}

// h1 = x @ W1, stored as FP16 (compute f32); W1 wave-uniform -> scalar loads
__global__ __launch_bounds__(256) void k_gemm1(const float* __restrict__ x,
                                               const float* __restrict__ W1,
                                               __half* __restrict__ h1) {
    int r = blockIdx.x * blockDim.x + threadIdx.x;
    if (r >= NN) return;
    const float* xr = x + (size_t)r * DF;
    float acc[HID];
#pragma unroll
    for (int c = 0; c < HID; ++c) acc[c] = 0.f;
#pragma unroll
    for (int k = 0; k < DF; k += 4) {
        float4 xv = *reinterpret_cast<const float4*>(xr + k);
#pragma unroll
        for (int c = 0; c < HID; ++c) {
            acc[c] += xv.x * W1[(k + 0) * HID + c];
            acc[c] += xv.y * W1[(k + 1) * HID + c];
            acc[c] += xv.z * W1[(k + 2) * HID + c];
            acc[c] += xv.w * W1[(k + 3) * HID + c];
        }
    }
    __half2 pack[HID / 2];
#pragma unroll
    for (int c = 0; c < HID; c += 2)
        pack[c / 2] = __floats2half2_rn(acc[c], acc[c + 1]);
    float4* dstp = reinterpret_cast<float4*>(h1 + (size_t)r * HID);
    const float4* srcp = reinterpret_cast<const float4*>(pack);
#pragma unroll
    for (int i = 0; i < 4; ++i) dstp[i] = srcp[i];
}

// gather-aggregate layer 1 (fp16 rows, one 64B line each), fused +b1/relu/@W2/reduce
__global__ void k_gather1(const int* __restrict__ rofs, const int* __restrict__ csr,
                          const float* __restrict__ dis, const __half* __restrict__ h1,
                          const float* __restrict__ b1, const float* __restrict__ W2,
                          float* __restrict__ h2) {
    int t = blockIdx.x * blockDim.x + threadIdx.x;
    int r = t >> 3;
    if (r >= NN) return;
    int p = t & 7;
    int start = rofs[r];
    int end = (r == NN - 1) ? NE : rofs[r + 1];
    float dr = dis[r];
    float a0 = 0.f, a1 = 0.f, a2 = 0.f, a3 = 0.f;
    int j = start;
    for (; j + 1 < end; j += 2) {
        int s0 = csr[j], s1 = csr[j + 1];
        float n0 = dr * dis[s0], n1 = dr * dis[s1];
        const __half2* q0 = reinterpret_cast<const __half2*>(h1 + (size_t)s0 * HID + p * 4);
        const __half2* q1 = reinterpret_cast<const __half2*>(h1 + (size_t)s1 * HID + p * 4);
        float2 u0 = __half22float2(q0[0]), u1 = __half22float2(q0[1]);
        float2 w0 = __half22float2(q1[0]), w1 = __half22float2(q1[1]);
        a0 += u0.x * n0 + w0.x * n1;
        a1 += u0.y * n0 + w0.y * n1;
        a2 += u1.x * n0 + w1.x * n1;
        a3 += u1.y * n0 + w1.y * n1;
    }
    if (j < end) {
        int s0 = csr[j];
        float n0 = dr * dis[s0];
        const __half2* q0 = reinterpret_cast<const __half2*>(h1 + (size_t)s0 * HID + p * 4);
        float2 u0 = __half22float2(q0[0]), u1 = __half22float2(q0[1]);
        a0 += u0.x * n0; a1 += u0.y * n0; a2 += u1.x * n0; a3 += u1.y * n0;
    }
    float self = dr * dr;
    const __half2* qs = reinterpret_cast<const __half2*>(h1 + (size_t)r * HID + p * 4);
    float2 s0v = __half22float2(qs[0]), s1v = __half22float2(qs[1]);
    a0 += s0v.x * self; a1 += s0v.y * self; a2 += s1v.x * self; a3 += s1v.y * self;
    float4 bv = *reinterpret_cast<const float4*>(b1 + p * 4);
    float v0 = fmaxf(a0 + bv.x, 0.f);
    float v1 = fmaxf(a1 + bv.y, 0.f);
    float v2 = fmaxf(a2 + bv.z, 0.f);
    float v3 = fmaxf(a3 + bv.w, 0.f);
    int c = p * 4;
    float o0 = v0 * W2[(c + 0) * NC + 0] + v1 * W2[(c + 1) * NC + 0] +
               v2 * W2[(c + 2) * NC + 0] + v3 * W2[(c + 3) * NC + 0];
    float o1 = v0 * W2[(c + 0) * NC + 1] + v1 * W2[(c + 1) * NC + 1] +
               v2 * W2[(c + 2) * NC + 1] + v3 * W2[(c + 3) * NC + 1];
    o0 += __shfl_xor(o0, 1); o1 += __shfl_xor(o1, 1);
    o0 += __shfl_xor(o0, 2); o1 += __shfl_xor(o1, 2);
    o0 += __shfl_xor(o0, 4); o1 += __shfl_xor(o1, 4);
    if (p == 0) {
        h2[2 * (size_t)r + 0] = o0;
        h2[2 * (size_t)r + 1] = o1;
    }
}

// gather-aggregate layer 2 (+b2) fused with log_softmax -> out
__global__ void k_gather2(const int* __restrict__ rofs, const int* __restrict__ csr,
                          const float* __restrict__ dis, const float* __restrict__ h2,
                          const float* __restrict__ b2, float* __restrict__ out) {
    int r = blockIdx.x * blockDim.x + threadIdx.x;
    if (r >= NN) return;
    int start = rofs[r];
    int end = (r == NN - 1) ? NE : rofs[r + 1];
    float dr = dis[r];
    float a0 = 0.f, a1 = 0.f;
    for (int j = start; j < end; ++j) {
        int s = csr[j];
        float nrm = dr * dis[s];
        float2 v = *reinterpret_cast<const float2*>(h2 + 2 * (size_t)s);
        a0 += v.x * nrm;
        a1 += v.y * nrm;
    }
    float self = dr * dr;
    float2 hv = *reinterpret_cast<const float2*>(h2 + 2 * (size_t)r);
    float l0 = a0 + hv.x * self + b2[0];
    float l1 = a1 + hv.y * self + b2[1];
    float m = fmaxf(l0, l1);
    float lse = m + logf(expf(l0 - m) + expf(l1 - m));
    out[2 * (size_t)r + 0] = l0 - lse;
    out[2 * (size_t)r + 1] = l1 - lse;
}

extern "C" void kernel_launch(void* const* d_in, const int* in_sizes, int n_in,
                              void* d_out, int out_size, void* d_ws, size_t ws_size,
                              hipStream_t stream) {
    const float* x  = (const float*)d_in[0];
    const int* ei   = (const int*)d_in[1];   // [2, NE] int32
    const float* W1 = (const float*)d_in[2];
    const float* b1 = (const float*)d_in[3];
    const float* W2 = (const float*)d_in[4];
    const float* b2 = (const float*)d_in[5];
    float* out      = (float*)d_out;

    float* ws       = (float*)d_ws;
    float* dis      = ws;
    int* rofs       = (int*)(ws + (size_t)NN);
    unsigned* btot  = (unsigned*)(ws + (size_t)2 * NN);
    int* bstart     = (int*)(ws + (size_t)2 * NN + 400);
    int* cursor     = (int*)(ws + (size_t)2 * NN + 800);
    float* h2       = ws + (size_t)2 * NN + 1200;
    int* csr        = (int*)(ws + (size_t)4 * NN + 1200);
    unsigned* scr   = (unsigned*)(ws + (size_t)4 * NN + 1200 + NE);  // NE words
    __half* h1      = (__half*)scr;  // 16NN halves; written after k_build consumes scr

    k_z<<<2, 256, 0, stream>>>(btot, NBUK);
    k_hist<<<391, 256, 0, stream>>>(ei + NE, btot);
    k_bscan<<<1, 512, 0, stream>>>(btot, bstart, cursor);
    k_part<<<391, 256, 0, stream>>>(ei, cursor, scr);
    k_build<<<NBUK, 256, 0, stream>>>(scr, bstart, rofs, dis, csr);
    k_gemm1<<<NB, 256, 0, stream>>>(x, W1, h1);
    k_gather1<<<(NN * 8 + 255) / 256, 256, 0, stream>>>(rofs, csr, dis, h1, b1, W2, h2);
    k_gather2<<<NB, 256, 0, stream>>>(rofs, csr, dis, h2, b2, out);
}